// Round 2
// baseline (95.401 us; speedup 1.0000x reference)
//
#include <hip/hip_runtime.h>
#include <math.h>

#define NQ 8
#define NL 2

// ---------------- DPP helpers (all VALU-pipe) ----------------
// Reduction step: v += dpp_mov(v) with old=0 for masked/invalid lanes.
template <int CTRL, int RM, int BM>
__device__ __forceinline__ float dpp_add(float v) {
    int o = __builtin_amdgcn_update_dpp(0, __float_as_int(v), CTRL, RM, BM, true);
    return v + __int_as_float(o);
}

// Full 64-lane sum -> broadcast (canonical GCN DPP reduction, result in lane 63).
__device__ __forceinline__ float wave_total(float v) {
    v = dpp_add<0xB1, 0xF, 0xF>(v);   // += lane^1 (quad_perm 1,0,3,2)
    v = dpp_add<0x4E, 0xF, 0xF>(v);   // += lane^2 (quad_perm 2,3,0,1)
    v = dpp_add<0x114, 0xF, 0xE>(v);  // row_shr:4, banks 1,2,3
    v = dpp_add<0x118, 0xF, 0xC>(v);  // row_shr:8, banks 2,3
    v = dpp_add<0x142, 0xA, 0xF>(v);  // row_bcast15 -> rows 1,3
    v = dpp_add<0x143, 0xC, 0xF>(v);  // row_bcast31 -> rows 2,3
    return __int_as_float(__builtin_amdgcn_readlane(__float_as_int(v), 63));
}

__device__ __forceinline__ float read_lane(float v, int l) {
    return __int_as_float(__builtin_amdgcn_readlane(__float_as_int(v), l));
}

// Partner value from lane^(1<<P), P in 0..5.
// P=0,1: quad_perm. P=2,3: two bank-masked row shifts (row_shl gives l+N,
// row_shr gives l-N; select banks whose bit P of lane is 0 / 1 resp.).
// P=4,5: LDS shuffle (only remaining LDS-pipe traffic in the gate loop).
template <int P>
__device__ __forceinline__ float partner(float v) {
    int vi = __float_as_int(v);
    if constexpr (P == 0) {
        return __int_as_float(__builtin_amdgcn_update_dpp(vi, vi, 0xB1, 0xF, 0xF, false));
    } else if constexpr (P == 1) {
        return __int_as_float(__builtin_amdgcn_update_dpp(vi, vi, 0x4E, 0xF, 0xF, false));
    } else if constexpr (P == 2) {
        int a = __builtin_amdgcn_update_dpp(vi, vi, 0x104, 0xF, 0x5, false); // shl:4 banks 0,2 (bit2=0 -> l+4)
        a = __builtin_amdgcn_update_dpp(a, vi, 0x114, 0xF, 0xA, false);      // shr:4 banks 1,3 (bit2=1 -> l-4)
        return __int_as_float(a);
    } else if constexpr (P == 3) {
        int a = __builtin_amdgcn_update_dpp(vi, vi, 0x108, 0xF, 0x3, false); // shl:8 banks 0,1
        a = __builtin_amdgcn_update_dpp(a, vi, 0x118, 0xF, 0xC, false);      // shr:8 banks 2,3
        return __int_as_float(a);
    } else if constexpr (P == 4) {
        return __shfl_xor(v, 16, 64);
    } else {
        return __shfl_xor(v, 32, 64);
    }
}

// ---------------- fused SU(2) gate ----------------
// U = [[a, -conj(b)], [b, conj(a)]]
struct SU2 { float ar, ai, br, bi; };

// In-register pair (amp0 = bit P clear, amp1 = bit P set).
__device__ __forceinline__ void pair_gate(float& r0, float& i0, float& r1, float& i1,
                                          const SU2 g) {
    float nr0 = g.ar * r0 - g.ai * i0 - g.br * r1 - g.bi * i1;
    float ni0 = g.ar * i0 + g.ai * r0 + g.bi * r1 - g.br * i1;
    float nr1 = g.br * r0 - g.bi * i0 + g.ar * r1 + g.ai * i1;
    float ni1 = g.br * i0 + g.bi * r0 + g.ar * i1 - g.ai * r1;
    r0 = nr0; i0 = ni0; r1 = nr1; i1 = ni1;
}

// State layout: lane holds amps idx = t*64+lane, t=0..3.
// idx bit p: p<6 -> lane bit p, p=6 -> t&1, p=7 -> t>>1.
template <int P>
__device__ __forceinline__ void apply_gate(int lane, float (&r)[4], float (&i)[4],
                                           const SU2 g) {
    if constexpr (P == 7) {
        pair_gate(r[0], i[0], r[2], i[2], g);
        pair_gate(r[1], i[1], r[3], i[3], g);
    } else if constexpr (P == 6) {
        pair_gate(r[0], i[0], r[1], i[1], g);
        pair_gate(r[2], i[2], r[3], i[3], g);
    } else {
        // new = A*mine + B*other; bit=0: A=a, B=-conj(b); bit=1: A=conj(a), B=b
        float sg = ((lane >> P) & 1) ? 1.0f : -1.0f;
        float Ai = -sg * g.ai;
        float Br =  sg * g.br;
#pragma unroll
        for (int t = 0; t < 4; ++t) {
            float pr = partner<P>(r[t]);
            float pi = partner<P>(i[t]);
            float nr = g.ar * r[t] - Ai * i[t] + Br * pr - g.bi * pi;
            float ni = g.ar * i[t] + Ai * r[t] + Br * pi + g.bi * pr;
            r[t] = nr; i[t] = ni;
        }
    }
}

// Compose U = [RZw(e)] * RYw(d) * RZ(c) * RY(b) * RX(a); all wave-uniform scalars.
// c*,s* are cos/sin of HALF the rotation angle; z = e^{-ic/2} = (zc, -zs).
template <bool LAST>
__device__ __forceinline__ SU2 compose(float ca, float sa, float cb, float sb,
                                       float zc, float zs, float cd, float sd,
                                       float wc, float ws) {
    // RY(b)*RX(a) = [[p, -conj(q)],[q, conj(p)]]
    float pr = cb * ca, pi = sb * sa;
    float qr = sb * ca, qi = -cb * sa;
    // RZ(c)*: alpha = z*p, beta = conj(z)*q
    float a1r = zc * pr + zs * pi, a1i = zc * pi - zs * pr;
    float b1r = zc * qr - zs * qi, b1i = zc * qi + zs * qr;
    // RYw(d)*
    float a2r = cd * a1r - sd * b1r, a2i = cd * a1i - sd * b1i;
    float b2r = sd * a1r + cd * b1r, b2i = sd * a1i + cd * b1i;
    if constexpr (LAST) {
        return {a2r, a2i, b2r, b2i};   // final RZw is diagonal before measurement: dropped
    } else {
        float a3r = wc * a2r + ws * a2i, a3i = wc * a2i - ws * a2r;
        float b3r = wc * b2r - ws * b2i, b3i = wc * b2i + ws * b2r;
        return {a3r, a3i, b3r, b3i};
    }
}

template <int L, int Q>
__device__ __forceinline__ void do_qubit(int lane, float (&r)[4], float (&i)[4],
                                         const float (&cc)[24], const float (&sc)[24],
                                         float vc, float vs) {
    constexpr int P = NQ - 1 - Q;        // wire 0 = MSB
    constexpr bool LAST = (L == NL - 1);
    float cd = read_lane(vc, 16 * L + Q);
    float sd = read_lane(vs, 16 * L + Q);
    float wc = 1.0f, ws = 0.0f;
    if constexpr (!LAST) {
        wc = read_lane(vc, 16 * L + Q + 8);
        ws = read_lane(vs, 16 * L + Q + 8);
    }
    SU2 g = compose<LAST>(cc[3 * Q], sc[3 * Q], cc[3 * Q + 1], sc[3 * Q + 1],
                          cc[3 * Q + 2], sc[3 * Q + 2], cd, sd, wc, ws);
    apply_gate<P>(lane, r, i, g);
}

__global__ __launch_bounds__(256) void qcritic_kernel(
    const float* __restrict__ x,    // [B,64]
    const float* __restrict__ Wad,  // [24,64]
    const float* __restrict__ bad,  // [24]
    const float* __restrict__ qw,   // [2,16] flat 32
    const float* __restrict__ Wfc,  // [8]
    const float* __restrict__ bfc,  // [1]
    float* __restrict__ out,        // [B]
    int B) {
    int tid  = threadIdx.x;
    int lane = tid & 63;
    int b    = blockIdx.x * 4 + (tid >> 6);
    if (b >= B) return;  // wave-uniform

    // ---- weight-angle trig, kept in lanes 0..31 of each wave (VALU broadcast later)
    float qv = qw[lane & 31];
    float vs_, vc_;
    sincosf(0.5f * qv, &vs_, &vc_);

    // ---- adapter u[j] = x[b].Wad[j] + bad[j]; t=atan(u); need cos/sin(t/2)
    // closed form: ct = rsqrt(1+u^2); ch = sqrt((1+ct)/2); sh = u*ct/(2*ch)
    float xv = x[b * 64 + lane];
    float cc[24], sc[24];
#pragma unroll
    for (int j = 0; j < 24; ++j) {
        float u  = wave_total(xv * Wad[j * 64 + lane]) + bad[j];
        float ct = rsqrtf(1.0f + u * u);
        float ch = sqrtf(0.5f * (1.0f + ct));
        cc[j] = ch;
        sc[j] = 0.5f * u * ct / ch;
    }

    // ---- init |0..0>
    float r[4] = {0.f, 0.f, 0.f, 0.f};
    float im[4] = {0.f, 0.f, 0.f, 0.f};
    if (lane == 0) r[0] = 1.0f;

    // ---- CZ-chain sign per amplitude (adjacent-bit pairs)
    float czs[4];
#pragma unroll
    for (int t = 0; t < 4; ++t) {
        int idx = t * 64 + lane;
        czs[t] = (__popc(idx & (idx >> 1)) & 1) ? -1.0f : 1.0f;
    }

    // ---- layer 0 (fused RX.RY.RZ.RYw.RZw per qubit) + CZ chain
    do_qubit<0, 0>(lane, r, im, cc, sc, vc_, vs_);
    do_qubit<0, 1>(lane, r, im, cc, sc, vc_, vs_);
    do_qubit<0, 2>(lane, r, im, cc, sc, vc_, vs_);
    do_qubit<0, 3>(lane, r, im, cc, sc, vc_, vs_);
    do_qubit<0, 4>(lane, r, im, cc, sc, vc_, vs_);
    do_qubit<0, 5>(lane, r, im, cc, sc, vc_, vs_);
    do_qubit<0, 6>(lane, r, im, cc, sc, vc_, vs_);
    do_qubit<0, 7>(lane, r, im, cc, sc, vc_, vs_);
#pragma unroll
    for (int t = 0; t < 4; ++t) { r[t] *= czs[t]; im[t] *= czs[t]; }

    // ---- layer 1 (fused RX.RY.RZ.RYw; RZw + CZ dropped: diagonal before |.|^2)
    do_qubit<1, 0>(lane, r, im, cc, sc, vc_, vs_);
    do_qubit<1, 1>(lane, r, im, cc, sc, vc_, vs_);
    do_qubit<1, 2>(lane, r, im, cc, sc, vc_, vs_);
    do_qubit<1, 3>(lane, r, im, cc, sc, vc_, vs_);
    do_qubit<1, 4>(lane, r, im, cc, sc, vc_, vs_);
    do_qubit<1, 5>(lane, r, im, cc, sc, vc_, vs_);
    do_qubit<1, 6>(lane, r, im, cc, sc, vc_, vs_);
    do_qubit<1, 7>(lane, r, im, cc, sc, vc_, vs_);

    // ---- readout: out[b] = bfc + sum_i |amp_i|^2 * g(i),
    // g(i) = sum_k Wfc[k]*(1-2*bit_{7-k}(i)); bits 0..5 from lane, 6,7 from t.
    float glow = 0.0f;
#pragma unroll
    for (int k = 2; k < 8; ++k)
        glow += Wfc[k] * (((lane >> (7 - k)) & 1) ? -1.0f : 1.0f);
    float w0 = Wfc[0], w1 = Wfc[1];
    float acc = 0.0f;
#pragma unroll
    for (int t = 0; t < 4; ++t) {
        float g = glow + ((t >> 1) ? -w0 : w0) + ((t & 1) ? -w1 : w1);
        acc += (r[t] * r[t] + im[t] * im[t]) * g;
    }
    float tot = wave_total(acc);
    if (lane == 0) out[b] = tot + bfc[0];
}

extern "C" void kernel_launch(void* const* d_in, const int* in_sizes, int n_in,
                              void* d_out, int out_size, void* d_ws, size_t ws_size,
                              hipStream_t stream) {
    const float* x   = (const float*)d_in[0];
    const float* Wad = (const float*)d_in[1];
    const float* bad = (const float*)d_in[2];
    const float* qw  = (const float*)d_in[3];
    const float* Wfc = (const float*)d_in[4];
    const float* bfc = (const float*)d_in[5];
    float* out = (float*)d_out;
    int B = in_sizes[0] / 64;
    int grid = (B + 3) / 4;
    qcritic_kernel<<<grid, 256, 0, stream>>>(x, Wad, bad, qw, Wfc, bfc, out, B);
}

// Round 3
// 80.222 us; speedup vs baseline: 1.1892x; 1.1892x over previous
//
#include <hip/hip_runtime.h>
#include <math.h>

typedef __attribute__((ext_vector_type(2))) float f32x2;

__device__ __forceinline__ f32x2 sp(float s) { f32x2 v; v.x = s; v.y = s; return v; }

// ---------------- DPP helpers (VALU-pipe) ----------------
template <int CTRL, int RM, int BM>
__device__ __forceinline__ float dpp_add(float v) {
    int o = __builtin_amdgcn_update_dpp(0, __float_as_int(v), CTRL, RM, BM, true);
    return v + __int_as_float(o);
}

// Full 64-lane sum (result broadcast via readlane 63).
__device__ __forceinline__ float wave_total(float v) {
    v = dpp_add<0xB1, 0xF, 0xF>(v);   // += lane^1
    v = dpp_add<0x4E, 0xF, 0xF>(v);   // += lane^2
    v = dpp_add<0x114, 0xF, 0xE>(v);  // row_shr:4
    v = dpp_add<0x118, 0xF, 0xC>(v);  // row_shr:8
    v = dpp_add<0x142, 0xA, 0xF>(v);  // row_bcast15
    v = dpp_add<0x143, 0xC, 0xF>(v);  // row_bcast31
    return __int_as_float(__builtin_amdgcn_readlane(__float_as_int(v), 63));
}

__device__ __forceinline__ float read_lane(float v, int l) {
    return __int_as_float(__builtin_amdgcn_readlane(__float_as_int(v), l));
}

// Partner value from lane^(1<<P), P in 0..5.
template <int P>
__device__ __forceinline__ float partner(float v) {
    int vi = __float_as_int(v);
    if constexpr (P == 0) {
        return __int_as_float(__builtin_amdgcn_update_dpp(vi, vi, 0xB1, 0xF, 0xF, false));
    } else if constexpr (P == 1) {
        return __int_as_float(__builtin_amdgcn_update_dpp(vi, vi, 0x4E, 0xF, 0xF, false));
    } else if constexpr (P == 2) {
        int a = __builtin_amdgcn_update_dpp(vi, vi, 0x104, 0xF, 0x5, false); // shl:4 banks 0,2
        a = __builtin_amdgcn_update_dpp(a, vi, 0x114, 0xF, 0xA, false);      // shr:4 banks 1,3
        return __int_as_float(a);
    } else if constexpr (P == 3) {
        int a = __builtin_amdgcn_update_dpp(vi, vi, 0x108, 0xF, 0x3, false); // shl:8 banks 0,1
        a = __builtin_amdgcn_update_dpp(a, vi, 0x118, 0xF, 0xC, false);      // shr:8 banks 2,3
        return __int_as_float(a);
    } else if constexpr (P == 4) {
        return __shfl_xor(v, 16, 64);
    } else {
        return __shfl_xor(v, 32, 64);
    }
}

template <int P>
__device__ __forceinline__ f32x2 partner2(f32x2 v) {
    f32x2 r; r.x = partner<P>(v.x); r.y = partner<P>(v.y); return r;
}

// ---------------- gate application ----------------
// U = [[a, -conj(b)], [b, conj(a)]], scalar pair (amp0: bit clear, amp1: bit set)
__device__ __forceinline__ void pair_gate(float& r0, float& i0, float& r1, float& i1,
                                          float ar, float ai, float br, float bi) {
    float nr0 = ar * r0 - ai * i0 - br * r1 - bi * i1;
    float ni0 = ar * i0 + ai * r0 + bi * r1 - br * i1;
    float nr1 = br * r0 - bi * i0 + ar * r1 + ai * i1;
    float ni1 = br * i0 + bi * r0 + ar * i1 - ai * r1;
    r0 = nr0; i0 = ni0; r1 = nr1; i1 = ni1;
}

// Packed pair: elementwise over the two halves (v_pk_fma candidates).
__device__ __forceinline__ void pair_gate2(f32x2& r0, f32x2& i0, f32x2& r1, f32x2& i1,
                                           float ar, float ai, float br, float bi) {
    f32x2 va = sp(ar), vi = sp(ai), vb = sp(br), vc = sp(bi);
    f32x2 nr0 = va * r0 - vi * i0 - vb * r1 - vc * i1;
    f32x2 ni0 = va * i0 + vi * r0 + vc * r1 - vb * i1;
    f32x2 nr1 = vb * r0 - vc * i0 + va * r1 + vi * i1;
    f32x2 ni1 = vb * i0 + vc * r0 + va * i1 - vi * r1;
    r0 = nr0; i0 = ni0; r1 = nr1; i1 = ni1;
}

// Cross-lane gate, packed state. State: lane holds amps idx=t*64+lane;
// A = {t0, t1}, B = {t2, t3}. idx bit p: p<6 lane bit, p=6 -> t&1, p=7 -> t>>1.
template <int P>
__device__ __forceinline__ void cross_gate(int lane, f32x2& Ar, f32x2& Ai, f32x2& Br, f32x2& Bi,
                                           float gar, float gai, float gbr, float gbi) {
    float sg = ((lane >> P) & 1) ? 1.0f : -1.0f;
    f32x2 vAr = sp(gar), vAi = sp(-sg * gai), vBr = sp(sg * gbr), vBi = sp(gbi);
    f32x2 pr = partner2<P>(Ar), pi = partner2<P>(Ai);
    f32x2 nAr = vAr * Ar - vAi * Ai + vBr * pr - vBi * pi;
    f32x2 nAi = vAr * Ai + vAi * Ar + vBr * pi + vBi * pr;
    Ar = nAr; Ai = nAi;
    pr = partner2<P>(Br); pi = partner2<P>(Bi);
    f32x2 nBr = vAr * Br - vAi * Bi + vBr * pr - vBi * pi;
    f32x2 nBi = vAr * Bi + vAi * Br + vBr * pi + vBi * pr;
    Br = nBr; Bi = nBi;
}

// Gate G (0..15): params live in lane G of (gar,gai,gbr,gbi) VGPRs.
template <int G>
__device__ __forceinline__ void apply_g(int lane, f32x2& Ar, f32x2& Ai, f32x2& Br, f32x2& Bi,
                                        float garv, float gaiv, float gbrv, float gbiv) {
    constexpr int Q = G & 7;
    constexpr int P = 7 - Q;  // wire 0 = MSB
    float ar = read_lane(garv, G), ai = read_lane(gaiv, G);
    float br = read_lane(gbrv, G), bi = read_lane(gbiv, G);
    if constexpr (P == 7) {
        // pairs (t0,t2)=(A.x,B.x), (t1,t3)=(A.y,B.y): elementwise packed
        pair_gate2(Ar, Ai, Br, Bi, ar, ai, br, bi);
    } else if constexpr (P == 6) {
        // pairs within each packed reg: (A.x,A.y), (B.x,B.y)
        float r0 = Ar.x, i0 = Ai.x, r1 = Ar.y, i1 = Ai.y;
        pair_gate(r0, i0, r1, i1, ar, ai, br, bi);
        Ar.x = r0; Ai.x = i0; Ar.y = r1; Ai.y = i1;
        r0 = Br.x; i0 = Bi.x; r1 = Br.y; i1 = Bi.y;
        pair_gate(r0, i0, r1, i1, ar, ai, br, bi);
        Br.x = r0; Bi.x = i0; Br.y = r1; Bi.y = i1;
    } else {
        cross_gate<P>(lane, Ar, Ai, Br, Bi, ar, ai, br, bi);
    }
}

__global__ __launch_bounds__(256) void qcritic_kernel(
    const float* __restrict__ x,    // [B,64]
    const float* __restrict__ Wad,  // [24,64]
    const float* __restrict__ bad,  // [24]
    const float* __restrict__ qw,   // [2,16] flat 32
    const float* __restrict__ Wfc,  // [8]
    const float* __restrict__ bfc,  // [1]
    float* __restrict__ out,        // [B]
    int B) {
    int tid = threadIdx.x;
    int lane = tid & 63;
    int b = blockIdx.x * 4 + (tid >> 6);
    if (b >= B) return;  // wave-uniform

    // ---- adapter: u[j] = x[b].Wad[j] + bad[j] (broadcast to all lanes) ----
    float xv = x[b * 64 + lane];
    float u[24];
#pragma unroll
    for (int j = 0; j < 24; ++j)
        u[j] = wave_total(xv * Wad[j * 64 + lane]) + bad[j];

    // ---- per-lane gate composition: lane g = 8*L + Q composes gate g ----
    int Q = lane & 7;
    int L = (lane >> 3) & 1;
    bool b0 = Q & 1, b1 = Q & 2, b2 = Q & 4;
    // select this lane's 3 data angles u[3Q..3Q+2] via cndmask tree
    float uq[3];
#pragma unroll
    for (int k = 0; k < 3; ++k) {
        float m01 = b0 ? u[3 + k] : u[0 + k];
        float m23 = b0 ? u[9 + k] : u[6 + k];
        float m45 = b0 ? u[15 + k] : u[12 + k];
        float m67 = b0 ? u[21 + k] : u[18 + k];
        float m03 = b1 ? m23 : m01;
        float m47 = b1 ? m67 : m45;
        uq[k] = b2 ? m47 : m03;
    }
    // closed-form half-angle trig of atan(u): ct=cos t; ch=cos(t/2); sh=sin(t/2)
    float ch[3], sh[3];
#pragma unroll
    for (int k = 0; k < 3; ++k) {
        float v = uq[k];
        float ct = rsqrtf(1.0f + v * v);
        ch[k] = sqrtf(0.5f * (1.0f + ct));
        sh[k] = __fdividef(0.5f * v * ct, ch[k]);
    }
    // weight-angle trig (RYw always; RZw only for layer 0 — layer-1 RZw is
    // diagonal before |.|^2 and dropped, like the trailing CZ chain)
    float cd, sd, wc, ws;
    __sincosf(0.5f * qw[(L << 4) + Q], &sd, &cd);
    __sincosf(0.5f * qw[(L << 4) + Q + 8], &ws, &wc);
    if (L == 1) { wc = 1.0f; ws = 0.0f; }
    // compose U = RZw * RYw * RZ * RY * RX  (all wave-register scalars)
    float ca = ch[0], sa = sh[0], cb = ch[1], sb = sh[1], zc = ch[2], zs = sh[2];
    float pr = cb * ca, pi = sb * sa;
    float qr = sb * ca, qi = -cb * sa;
    float a1r = zc * pr + zs * pi, a1i = zc * pi - zs * pr;
    float b1r = zc * qr - zs * qi, b1i = zc * qi + zs * qr;
    float a2r = cd * a1r - sd * b1r, a2i = cd * a1i - sd * b1i;
    float b2r = sd * a1r + cd * b1r, b2i = sd * a1i + cd * b1i;
    float garv = wc * a2r + ws * a2i, gaiv = wc * a2i - ws * a2r;
    float gbrv = wc * b2r - ws * b2i, gbiv = wc * b2i + ws * b2r;

    // ---- init |0..0> ----
    f32x2 Ar, Ai, Br, Bi;
    Ar.x = (lane == 0) ? 1.0f : 0.0f; Ar.y = 0.0f;
    Ai = sp(0.0f); Br = sp(0.0f); Bi = sp(0.0f);

    // ---- CZ-chain signs (after layer 0 only) ----
    f32x2 czA, czB;
    {
        int i0 = lane, i1 = 64 + lane, i2 = 128 + lane, i3 = 192 + lane;
        czA.x = (__popc(i0 & (i0 >> 1)) & 1) ? -1.0f : 1.0f;
        czA.y = (__popc(i1 & (i1 >> 1)) & 1) ? -1.0f : 1.0f;
        czB.x = (__popc(i2 & (i2 >> 1)) & 1) ? -1.0f : 1.0f;
        czB.y = (__popc(i3 & (i3 >> 1)) & 1) ? -1.0f : 1.0f;
    }

    // ---- layer 0 ----
    apply_g<0>(lane, Ar, Ai, Br, Bi, garv, gaiv, gbrv, gbiv);
    apply_g<1>(lane, Ar, Ai, Br, Bi, garv, gaiv, gbrv, gbiv);
    apply_g<2>(lane, Ar, Ai, Br, Bi, garv, gaiv, gbrv, gbiv);
    apply_g<3>(lane, Ar, Ai, Br, Bi, garv, gaiv, gbrv, gbiv);
    apply_g<4>(lane, Ar, Ai, Br, Bi, garv, gaiv, gbrv, gbiv);
    apply_g<5>(lane, Ar, Ai, Br, Bi, garv, gaiv, gbrv, gbiv);
    apply_g<6>(lane, Ar, Ai, Br, Bi, garv, gaiv, gbrv, gbiv);
    apply_g<7>(lane, Ar, Ai, Br, Bi, garv, gaiv, gbrv, gbiv);
    Ar *= czA; Ai *= czA; Br *= czB; Bi *= czB;

    // ---- layer 1 ----
    apply_g<8>(lane, Ar, Ai, Br, Bi, garv, gaiv, gbrv, gbiv);
    apply_g<9>(lane, Ar, Ai, Br, Bi, garv, gaiv, gbrv, gbiv);
    apply_g<10>(lane, Ar, Ai, Br, Bi, garv, gaiv, gbrv, gbiv);
    apply_g<11>(lane, Ar, Ai, Br, Bi, garv, gaiv, gbrv, gbiv);
    apply_g<12>(lane, Ar, Ai, Br, Bi, garv, gaiv, gbrv, gbiv);
    apply_g<13>(lane, Ar, Ai, Br, Bi, garv, gaiv, gbrv, gbiv);
    apply_g<14>(lane, Ar, Ai, Br, Bi, garv, gaiv, gbrv, gbiv);
    apply_g<15>(lane, Ar, Ai, Br, Bi, garv, gaiv, gbrv, gbiv);

    // ---- readout: out[b] = bfc + sum_i |amp_i|^2 * g(i) ----
    float glow = 0.0f;
#pragma unroll
    for (int k = 2; k < 8; ++k)
        glow += Wfc[k] * (((lane >> (7 - k)) & 1) ? -1.0f : 1.0f);
    float w0 = Wfc[0], w1 = Wfc[1];
    f32x2 gA, gB;
    gA.x = glow + w0 + w1; gA.y = glow + w0 - w1;
    gB.x = glow - w0 + w1; gB.y = glow - w0 - w1;
    f32x2 acc2 = (Ar * Ar + Ai * Ai) * gA + (Br * Br + Bi * Bi) * gB;
    float tot = wave_total(acc2.x + acc2.y);
    if (lane == 0) out[b] = tot + bfc[0];
}

extern "C" void kernel_launch(void* const* d_in, const int* in_sizes, int n_in,
                              void* d_out, int out_size, void* d_ws, size_t ws_size,
                              hipStream_t stream) {
    const float* x   = (const float*)d_in[0];
    const float* Wad = (const float*)d_in[1];
    const float* bad = (const float*)d_in[2];
    const float* qw  = (const float*)d_in[3];
    const float* Wfc = (const float*)d_in[4];
    const float* bfc = (const float*)d_in[5];
    float* out = (float*)d_out;
    int B = in_sizes[0] / 64;
    int grid = (B + 3) / 4;
    qcritic_kernel<<<grid, 256, 0, stream>>>(x, Wad, bad, qw, Wfc, bfc, out, B);
}